// Round 2
// baseline (326.448 us; speedup 1.0000x reference)
//
#include <hip/hip_runtime.h>
#include <hip/hip_bf16.h>

#define N_S 16384
#define LL 10
#define DD 256

typedef __bf16 bf16;
typedef __attribute__((ext_vector_type(8))) __bf16 bf16x8_t;
typedef __attribute__((ext_vector_type(4))) __bf16 bf16x4_t;
typedef __attribute__((ext_vector_type(4))) float f32x4_t;

// cos with explicit revolution reduction (v_cos_f32 takes revolutions)
__device__ __forceinline__ float fast_cos(float x) {
    float r = x * 0.15915494309189535f;   // x / (2*pi)
    r = r - rintf(r);                     // reduce to [-0.5, 0.5]
    return __builtin_amdgcn_cosf(r);
}

__device__ __forceinline__ float bf2f(unsigned short u) {
    return __uint_as_float((unsigned)u << 16);
}

// ---------------------------------------------------------------------------
// K0: precompute factored weight matrices (packed for MFMA B-fragments) and
// exact bias-fold vectors.
//   Acat[kk][nn]  (K=256, N=512): A_h = wq_h^T @ wk_h,  nn = h*256 + j
//   Ccat[kk][oo]  (K=512, N=256): C_h = wv_h^T @ wout_h^T, kk = h*256 + i
//   u[512]   : bq_h @ wk_h          (added to G columns)
//   p[512]   : wq_h^T @ bk_h        (s0 = m_last . p_h + c_h)
//   c2[2]    : bq_h . bk_h
//   dvec[256]: b_out + sum bv . wout
// ---------------------------------------------------------------------------
__global__ __launch_bounds__(256) void k_pre(
    const float* __restrict__ w_in, const float* __restrict__ b_in,
    const float* __restrict__ w_out, const float* __restrict__ b_out,
    bf16* __restrict__ Apk, bf16* __restrict__ Cpk,
    float* __restrict__ u, float* __restrict__ p,
    float* __restrict__ c2, float* __restrict__ dvec)
{
    const int bid = blockIdx.x;
    const int tid = threadIdx.x;
    if (bid < 512) {
        const int g = bid * 256 + tid;      // 0..131071
        // ----- Acat element (kk, nn) -----
        {
            const int kk = g >> 9;          // 0..255
            const int nn = g & 511;         // 0..511
            const int h = nn >> 8;
            const int j = nn & 255;
            const float* wq = w_in + (size_t)(h * 128) * 256;
            const float* wk = w_in + (size_t)(256 + h * 128) * 256;
            float s = 0.f;
            for (int d = 0; d < 128; ++d)
                s += wq[d * 256 + kk] * wk[d * 256 + j];
            // pack into B-fragment order for K1 (K=256 -> 8 ksteps, N=512 -> 32 nblk)
            const int lane = (((kk & 31) >> 3) << 4) + (nn & 15);
            const int idx = ((((nn >> 4) * 8 + (kk >> 5)) * 64 + lane) << 3) + (kk & 7);
            Apk[idx] = (bf16)s;
        }
        // ----- Ccat element (kk2, oo) -----
        {
            const int oo = g >> 9;          // 0..255
            const int kk2 = g & 511;        // 0..511
            const int h = kk2 >> 8;
            const int i = kk2 & 255;
            const float* wv = w_in + (size_t)(512 + h * 128) * 256;
            float s = 0.f;
            for (int d = 0; d < 128; ++d)
                s += wv[d * 256 + i] * w_out[oo * 256 + h * 128 + d];
            // pack for K3 (K=512 -> 16 ksteps, N=256 -> 16 nblk)
            const int lane = (((kk2 & 31) >> 3) << 4) + (oo & 15);
            const int idx = ((((oo >> 4) * 16 + (kk2 >> 5)) * 64 + lane) << 3) + (kk2 & 7);
            Cpk[idx] = (bf16)s;
        }
    } else {
        // small bias-fold vectors (exact handling; zeros for this setup)
        for (int j = tid; j < 512; j += 256) {
            const int h = j >> 8; const int jj = j & 255;
            float s = 0.f;
            for (int d = 0; d < 128; ++d)
                s += b_in[h * 128 + d] * w_in[(size_t)(256 + h * 128 + d) * 256 + jj];
            u[j] = s;
        }
        for (int i = tid; i < 512; i += 256) {
            const int h = i >> 8; const int ii = i & 255;
            float s = 0.f;
            for (int d = 0; d < 128; ++d)
                s += w_in[(size_t)(h * 128 + d) * 256 + ii] * b_in[256 + h * 128 + d];
            p[i] = s;
        }
        if (tid < 2) {
            float s = 0.f;
            for (int d = 0; d < 128; ++d)
                s += b_in[tid * 128 + d] * b_in[256 + tid * 128 + d];
            c2[tid] = s;
        }
        if (tid < 256) {
            float s = b_out[tid];
            for (int t = 0; t < 256; ++t)
                s += b_in[512 + t] * w_out[tid * 256 + t];
            dvec[tid] = s;
        }
    }
}

// ---------------------------------------------------------------------------
// K1: G[16384][512] (bf16) = m_last @ Acat + u      MFMA 16x16x32 bf16
// block = 4 waves, tile 128(M) x 64(N), K=256
// ---------------------------------------------------------------------------
__global__ __launch_bounds__(256) void k_gemm1(
    const float* __restrict__ messages, const bf16* __restrict__ Apk,
    const float* __restrict__ u, bf16* __restrict__ G)
{
    const int lane = threadIdx.x & 63;
    const int wid = threadIdx.x >> 6;
    const int mblk = blockIdx.x;            // 0..127
    const int nblk = blockIdx.y;            // 0..7
    const int m0 = mblk * 128 + wid * 32;
    const int r16 = lane & 15;
    const int q4 = lane >> 4;

    f32x4_t acc[2][4];
    #pragma unroll
    for (int a = 0; a < 2; ++a)
        #pragma unroll
        for (int b = 0; b < 4; ++b)
            acc[a][b] = (f32x4_t)(0.f);

    #pragma unroll
    for (int ks = 0; ks < 8; ++ks) {
        bf16x8_t afr[2];
        #pragma unroll
        for (int mt = 0; mt < 2; ++mt) {
            const int row = m0 + mt * 16 + r16;
            const float* src = messages + (size_t)row * (LL * DD) + (LL - 1) * DD + ks * 32 + q4 * 8;
            f32x4_t lo = *(const f32x4_t*)(src);
            f32x4_t hi = *(const f32x4_t*)(src + 4);
            bf16x8_t a;
            a[0] = (bf16)lo[0]; a[1] = (bf16)lo[1]; a[2] = (bf16)lo[2]; a[3] = (bf16)lo[3];
            a[4] = (bf16)hi[0]; a[5] = (bf16)hi[1]; a[6] = (bf16)hi[2]; a[7] = (bf16)hi[3];
            afr[mt] = a;
        }
        #pragma unroll
        for (int nt = 0; nt < 4; ++nt) {
            const int nblk16 = nblk * 4 + nt;
            bf16x8_t b = *(const bf16x8_t*)(Apk + (((size_t)(nblk16 * 8 + ks) * 64 + lane) << 3));
            #pragma unroll
            for (int mt = 0; mt < 2; ++mt)
                acc[mt][nt] = __builtin_amdgcn_mfma_f32_16x16x32_bf16(afr[mt], b, acc[mt][nt], 0, 0, 0);
        }
    }
    #pragma unroll
    for (int mt = 0; mt < 2; ++mt)
        #pragma unroll
        for (int nt = 0; nt < 4; ++nt) {
            const int col = nblk * 64 + nt * 16 + r16;
            const float ub = u[col];
            #pragma unroll
            for (int r = 0; r < 4; ++r) {
                const int row = m0 + mt * 16 + q4 * 4 + r;
                G[(size_t)row * 512 + col] = (bf16)(acc[mt][nt][r] + ub);
            }
        }
}

// ---------------------------------------------------------------------------
// K2: per-sample attention. One wave per sample; lane owns d = lane*4..+3.
// Reads G row (g0,g1), computes te=cos(delta*w_time+b_time), scores, softmax
// over valid keys only (skips masked message rows entirely), writes ycat bf16
// IN PLACE over the G row.
// ---------------------------------------------------------------------------
__global__ __launch_bounds__(256) void k_attn(
    const float* __restrict__ messages, const float* __restrict__ timestamps,
    const float* __restrict__ w_time, const float* __restrict__ b_time,
    const int* __restrict__ lengths, const float* __restrict__ p,
    const float* __restrict__ c2, bf16* __restrict__ GY)
{
    const int lane = threadIdx.x & 63;
    const int wid = threadIdx.x >> 6;
    const int n = blockIdx.x * 4 + wid;
    const int d0 = lane * 4;

    // G row (both heads' g vectors)
    const unsigned short* Grow = (const unsigned short*)(GY + (size_t)n * 512);
    float g0[4], g1[4];
    {
        ushort4 a = *(const ushort4*)(Grow + d0);
        ushort4 b = *(const ushort4*)(Grow + 256 + d0);
        g0[0] = bf2f(a.x); g0[1] = bf2f(a.y); g0[2] = bf2f(a.z); g0[3] = bf2f(a.w);
        g1[0] = bf2f(b.x); g1[1] = bf2f(b.y); g1[2] = bf2f(b.z); g1[3] = bf2f(b.w);
    }

    float wt[4], bt[4], m9[4];
    *(f32x4_t*)wt = *(const f32x4_t*)(w_time + d0);
    *(f32x4_t*)bt = *(const f32x4_t*)(b_time + d0);
    *(f32x4_t*)m9 = *(const f32x4_t*)(messages + (size_t)n * (LL * DD) + (LL - 1) * DD + d0);

    const float* tsrow = timestamps + n * LL;
    const float tlast = tsrow[LL - 1];
    const int valid = lengths[n] + 1;       // 1..10
    const int lmin = LL - valid;            // 0..9

    // s0 = m_last . p_h + c_h   (exact bias term; zero for this setup)
    float s0a, s0b;
    {
        f32x4_t p0 = *(const f32x4_t*)(p + d0);
        f32x4_t p1 = *(const f32x4_t*)(p + 256 + d0);
        s0a = m9[0] * p0[0] + m9[1] * p0[1] + m9[2] * p0[2] + m9[3] * p0[3];
        s0b = m9[0] * p1[0] + m9[1] * p1[1] + m9[2] * p1[2] + m9[3] * p1[3];
        #pragma unroll
        for (int m = 1; m < 64; m <<= 1) {
            s0a += __shfl_xor(s0a, m);
            s0b += __shfl_xor(s0b, m);
        }
        s0a += c2[0];
        s0b += c2[1];
    }

    const float scale = 0.08838834764831845f;   // 1/sqrt(128)
    float sc0[LL], sc1[LL];
    #pragma unroll
    for (int l = 0; l < LL; ++l) {
        if (l >= lmin) {                         // wave-uniform branch
            const float delta = tsrow[l] - tlast;
            float pa = 0.f, pb = 0.f;
            #pragma unroll
            for (int j = 0; j < 4; ++j) {
                const float te = fast_cos(delta * wt[j] + bt[j]);
                pa += g0[j] * te;
                pb += g1[j] * te;
            }
            #pragma unroll
            for (int m = 1; m < 64; m <<= 1) {
                pa += __shfl_xor(pa, m);
                pb += __shfl_xor(pb, m);
            }
            sc0[l] = (pa + s0a) * scale;
            sc1[l] = (pb + s0b) * scale;
        } else {
            sc0[l] = -1e30f;
            sc1[l] = -1e30f;
        }
    }

    // softmax (all lanes hold identical full sums after butterfly)
    float mx0 = sc0[0], mx1 = sc1[0];
    #pragma unroll
    for (int l = 1; l < LL; ++l) {
        mx0 = fmaxf(mx0, sc0[l]);
        mx1 = fmaxf(mx1, sc1[l]);
    }
    float w0[LL], w1[LL];
    float den0 = 0.f, den1 = 0.f;
    #pragma unroll
    for (int l = 0; l < LL; ++l) {
        w0[l] = (l >= lmin) ? __expf(sc0[l] - mx0) : 0.f;
        w1[l] = (l >= lmin) ? __expf(sc1[l] - mx1) : 0.f;
        den0 += w0[l];
        den1 += w1[l];
    }
    const float inv0 = 1.f / den0, inv1 = 1.f / den1;

    // y = attn-weighted sum of message rows (skip masked rows -> no load)
    float y0[4] = {0.f, 0.f, 0.f, 0.f}, y1[4] = {0.f, 0.f, 0.f, 0.f};
    #pragma unroll
    for (int l = 0; l < LL; ++l) {
        if (l >= lmin) {
            float mv[4];
            if (l == LL - 1) {
                mv[0] = m9[0]; mv[1] = m9[1]; mv[2] = m9[2]; mv[3] = m9[3];
            } else {
                *(f32x4_t*)mv = *(const f32x4_t*)(messages + (size_t)n * (LL * DD) + l * DD + d0);
            }
            const float a0 = w0[l] * inv0, a1 = w1[l] * inv1;
            #pragma unroll
            for (int j = 0; j < 4; ++j) {
                y0[j] += a0 * mv[j];
                y1[j] += a1 * mv[j];
            }
        }
    }

    // write ycat (bf16) in place over the G row
    bf16x4_t v0, v1;
    v0[0] = (bf16)y0[0]; v0[1] = (bf16)y0[1]; v0[2] = (bf16)y0[2]; v0[3] = (bf16)y0[3];
    v1[0] = (bf16)y1[0]; v1[1] = (bf16)y1[1]; v1[2] = (bf16)y1[2]; v1[3] = (bf16)y1[3];
    *(bf16x4_t*)(GY + (size_t)n * 512 + d0) = v0;
    *(bf16x4_t*)(GY + (size_t)n * 512 + 256 + d0) = v1;
}

// ---------------------------------------------------------------------------
// K3: out[16384][256] (fp32) = Y @ Ccat + dvec      MFMA 16x16x32 bf16
// ---------------------------------------------------------------------------
__global__ __launch_bounds__(256) void k_gemm2(
    const bf16* __restrict__ Y, const bf16* __restrict__ Cpk,
    const float* __restrict__ dvec, float* __restrict__ out)
{
    const int lane = threadIdx.x & 63;
    const int wid = threadIdx.x >> 6;
    const int mblk = blockIdx.x;            // 0..127
    const int nblk = blockIdx.y;            // 0..3
    const int m0 = mblk * 128 + wid * 32;
    const int r16 = lane & 15;
    const int q4 = lane >> 4;

    f32x4_t acc[2][4];
    #pragma unroll
    for (int a = 0; a < 2; ++a)
        #pragma unroll
        for (int b = 0; b < 4; ++b)
            acc[a][b] = (f32x4_t)(0.f);

    #pragma unroll
    for (int ks = 0; ks < 16; ++ks) {
        bf16x8_t afr[2];
        #pragma unroll
        for (int mt = 0; mt < 2; ++mt) {
            const int row = m0 + mt * 16 + r16;
            afr[mt] = *(const bf16x8_t*)(Y + (size_t)row * 512 + ks * 32 + q4 * 8);
        }
        #pragma unroll
        for (int nt = 0; nt < 4; ++nt) {
            const int nblk16 = nblk * 4 + nt;
            bf16x8_t b = *(const bf16x8_t*)(Cpk + (((size_t)(nblk16 * 16 + ks) * 64 + lane) << 3));
            #pragma unroll
            for (int mt = 0; mt < 2; ++mt)
                acc[mt][nt] = __builtin_amdgcn_mfma_f32_16x16x32_bf16(afr[mt], b, acc[mt][nt], 0, 0, 0);
        }
    }
    #pragma unroll
    for (int mt = 0; mt < 2; ++mt)
        #pragma unroll
        for (int nt = 0; nt < 4; ++nt) {
            const int col = nblk * 64 + nt * 16 + r16;
            const float db = dvec[col];
            #pragma unroll
            for (int r = 0; r < 4; ++r) {
                const int row = m0 + mt * 16 + q4 * 4 + r;
                out[(size_t)row * 256 + col] = acc[mt][nt][r] + db;
            }
        }
}

// ---------------------------------------------------------------------------
extern "C" void kernel_launch(void* const* d_in, const int* in_sizes, int n_in,
                              void* d_out, int out_size, void* d_ws, size_t ws_size,
                              hipStream_t stream) {
    const float* messages   = (const float*)d_in[0];
    const float* timestamps = (const float*)d_in[1];
    const float* w_time     = (const float*)d_in[2];
    const float* b_time     = (const float*)d_in[3];
    const float* w_in       = (const float*)d_in[4];
    const float* b_in       = (const float*)d_in[5];
    const float* w_out      = (const float*)d_in[6];
    const float* b_out      = (const float*)d_in[7];
    const int*   lengths    = (const int*)d_in[8];
    float* out = (float*)d_out;

    char* ws = (char*)d_ws;
    bf16*  Apk  = (bf16*)(ws);                 // 256 KiB
    bf16*  Cpk  = (bf16*)(ws + 262144);        // 256 KiB
    float* u    = (float*)(ws + 524288);       // 2 KiB
    float* p    = (float*)(ws + 526336);       // 2 KiB
    float* c2   = (float*)(ws + 528384);       // 8 B
    float* dvec = (float*)(ws + 528448);       // 1 KiB
    bf16*  GY   = (bf16*)(ws + 1048576);       // 16 MiB (G, then Y in place)

    k_pre<<<dim3(513), dim3(256), 0, stream>>>(w_in, b_in, w_out, b_out,
                                               Apk, Cpk, u, p, c2, dvec);
    k_gemm1<<<dim3(128, 8), dim3(256), 0, stream>>>(messages, Apk, u, GY);
    k_attn<<<dim3(4096), dim3(256), 0, stream>>>(messages, timestamps, w_time, b_time,
                                                 lengths, p, c2, GY);
    k_gemm2<<<dim3(128, 4), dim3(256), 0, stream>>>(GY, Cpk, dvec, out);
}